// Round 18
// baseline (123.179 us; speedup 1.0000x reference)
//
#include <hip/hip_runtime.h>
#include <hip/hip_bf16.h>

typedef __hip_bfloat16 bf16;
typedef __attribute__((ext_vector_type(8))) short bf16x8;
typedef __attribute__((ext_vector_type(4))) float f32x4;
typedef __attribute__((ext_vector_type(4))) short s16x4;

constexpr int B_ = 2, N_ = 2048, E_ = 1024, H_ = 16, KD_ = 64;
constexpr int M_ = B_ * N_;                 // 4096 token rows
constexpr float SCALE = 0.25f * 1.44269504088896f;  // (1/4) * log2(e), folded into K

#define MFMA16(A, Bf, C) __builtin_amdgcn_mfma_f32_16x16x32_bf16(A, Bf, C, 0, 0, 0)
#define SBAR() do { __builtin_amdgcn_s_barrier(); __builtin_amdgcn_sched_barrier(0); } while (0)
#define WAITCNT(s) asm volatile("s_waitcnt " s ::: "memory")
#define SETPRIO(p) __builtin_amdgcn_s_setprio(p)

typedef const __attribute__((address_space(1))) void* gptr_t;
typedef __attribute__((address_space(3))) void* sptr_t;

__device__ inline short bf16bits(float f) {
  bf16 h = __float2bfloat16(f);
  short s;
  __builtin_memcpy(&s, &h, 2);
  return s;
}
__device__ inline float bf16f(short s) {
  bf16 h;
  __builtin_memcpy(&h, &s, 2);
  return __bfloat162float(h);
}

// ---------------------------------------------------------------------------
// Stage NROWS x 128 bytes global->LDS with the XOR swizzle
// (logical (row,slot16) at byte row*128 + ((slot*16) ^ ((row&7)<<4))).
// Pre-swizzled SOURCE + linear global_load_lds dest (rule #21).
// ---------------------------------------------------------------------------
template <int NROWS, int NTHR>
__device__ inline void stageT(const bf16* __restrict__ base, int stride_elems,
                              char* lds) {
  const int t = threadIdx.x;
#pragma unroll
  for (int i = 0; i < NROWS * 128 / (NTHR * 16); i++) {
    int L = i * NTHR * 16 + t * 16;               // linear LDS byte offset
    int row = L >> 7;
    int slot = ((L >> 4) & 7) ^ (row & 7);        // inverse of the XOR swizzle
    const bf16* src = base + (size_t)row * stride_elems + slot * 8;
    __builtin_amdgcn_global_load_lds((gptr_t)(const void*)src,
                                     (sptr_t)(void*)(lds + L), 16, 0, 0);
  }
}

// Read one MFMA A/B fragment (8 bf16 along k) from a swizzled tile (128B rows).
__device__ inline bf16x8 frag_ld(const char* lds, int row, int ks) {
  const int g = (threadIdx.x >> 4) & 3;           // lane>>4 within wave
  const int off = (ks * 64 + g * 16) ^ ((row & 7) << 4);
  return *(const bf16x8*)(lds + row * 128 + off);
}

// ---------------------------------------------------------------------------
// Elementwise fp32 -> bf16 for x, Wq, Wk, Wv, Wp (contiguous dst).
// ---------------------------------------------------------------------------
__global__ __launch_bounds__(256) void cvt_all(
    const float* __restrict__ x, const float* __restrict__ wq,
    const float* __restrict__ wk, const float* __restrict__ wv,
    const float* __restrict__ wp, bf16* __restrict__ dst) {
  const size_t XN = (size_t)M_ * E_;              // 4M
  const size_t WN = (size_t)E_ * E_;              // 1M
  size_t i = ((size_t)blockIdx.x * 256 + threadIdx.x) * 4;
  const float* src;
  size_t off;
  if (i < XN) { src = x; off = i; }
  else if (i < XN + WN) { src = wq; off = i - XN; }
  else if (i < XN + 2 * WN) { src = wk; off = i - XN - WN; }
  else if (i < XN + 3 * WN) { src = wv; off = i - XN - 2 * WN; }
  else { src = wp; off = i - XN - 3 * WN; }
  float4 v = *(const float4*)(src + off);
  s16x4 o;
  o[0] = bf16bits(v.x); o[1] = bf16bits(v.y);
  o[2] = bf16bits(v.z); o[3] = bf16bits(v.w);
  *(s16x4*)(dst + i) = o;
}

// ---------------------------------------------------------------------------
// Fused QKV GEMM: [Q|K|V] = x @ Wqkv^T + b.  128x128 tile, BK=64, 4 waves.
// Q head-major; K head-major PRE-SCALED by (1/4)*log2(e); V transposed heads.
// ---------------------------------------------------------------------------
__global__ __launch_bounds__(256) void gemm_qkv(
    const bf16* __restrict__ A, const bf16* __restrict__ Wb,
    const float* __restrict__ bq, const float* __restrict__ bk,
    const float* __restrict__ bv, bf16* __restrict__ Qhd,
    bf16* __restrict__ Khd, bf16* __restrict__ Vtd) {
  __shared__ char Asm[16384];
  __shared__ char Bsm[16384];
  const int t = threadIdx.x, lane = t & 63, w = t >> 6;
  const int wr = w >> 1, wc = w & 1;
  const int c = lane & 15, g = lane >> 4;
  const int row0 = blockIdx.y * 128, col0 = blockIdx.x * 128;
  f32x4 acc[4][4] = {};

  for (int k0 = 0; k0 < E_; k0 += 64) {
    stageT<64, 256>(A + (size_t)row0 * E_ + k0, E_, Asm);
    stageT<64, 256>(A + (size_t)(row0 + 64) * E_ + k0, E_, Asm + 8192);
    stageT<64, 256>(Wb + (size_t)col0 * E_ + k0, E_, Bsm);
    stageT<64, 256>(Wb + (size_t)(col0 + 64) * E_ + k0, E_, Bsm + 8192);
    __syncthreads();
#pragma unroll
    for (int ks = 0; ks < 2; ks++) {
      bf16x8 af[4], bfr[4];
#pragma unroll
      for (int mi = 0; mi < 4; mi++) af[mi] = frag_ld(Asm, wr * 64 + mi * 16 + c, ks);
#pragma unroll
      for (int ni = 0; ni < 4; ni++) bfr[ni] = frag_ld(Bsm, wc * 64 + ni * 16 + c, ks);
#pragma unroll
      for (int mi = 0; mi < 4; mi++)
#pragma unroll
        for (int ni = 0; ni < 4; ni++)
          acc[mi][ni] = MFMA16(af[mi], bfr[ni], acc[mi][ni]);
    }
    __syncthreads();
  }

  const int sel = col0 >> 10;                     // 0:Q 1:K 2:V (uniform)
  const float* biasp = sel == 0 ? bq : sel == 1 ? bk : bv;
  bf16* outp = sel == 0 ? Qhd : sel == 1 ? Khd : Vtd;
#pragma unroll
  for (int mi = 0; mi < 4; mi++) {
#pragma unroll
    for (int ni = 0; ni < 4; ni++) {
      const int row = row0 + wr * 64 + mi * 16 + g * 4;
      const int col = col0 + wc * 64 + ni * 16 + c;
      const int ccol = col & 1023, h = ccol >> 6, kd = ccol & 63;
      const float bvf = biasp[ccol];
      if (sel < 2) {
        const float scl = (sel == 1) ? SCALE : 1.0f;
#pragma unroll
        for (int r = 0; r < 4; r++) {
          const int rr = row + r, b = rr >> 11, n = rr & (N_ - 1);
          outp[(((size_t)(b * H_ + h)) * N_ + n) * KD_ + kd] =
              __float2bfloat16((acc[mi][ni][r] + bvf) * scl);
        }
      } else {
        const int b = row >> 11, n = row & (N_ - 1);
        s16x4 o;
#pragma unroll
        for (int r = 0; r < 4; r++) o[r] = bf16bits(acc[mi][ni][r] + bvf);
        *(s16x4*)&outp[(((size_t)(b * H_ + h)) * KD_ + kd) * N_ + n] = o;
      }
    }
  }
}

// ---------------------------------------------------------------------------
// Projection GEMM: out(fp32) = attn @ Wp^T + bp.  128x64 tile -> 512 blocks.
// ---------------------------------------------------------------------------
__global__ __launch_bounds__(256) void gemm_proj(
    const bf16* __restrict__ A, const bf16* __restrict__ Wb,
    const float* __restrict__ bias, float* __restrict__ outf) {
  __shared__ char Asm[16384];
  __shared__ char Bsm[8192];
  const int t = threadIdx.x, lane = t & 63, w = t >> 6;
  const int wr = w >> 1, wc = w & 1;
  const int c = lane & 15, g = lane >> 4;
  const int row0 = blockIdx.y * 128, col0 = blockIdx.x * 64;
  f32x4 acc[4][2] = {};

  for (int k0 = 0; k0 < E_; k0 += 64) {
    stageT<64, 256>(A + (size_t)row0 * E_ + k0, E_, Asm);
    stageT<64, 256>(A + (size_t)(row0 + 64) * E_ + k0, E_, Asm + 8192);
    stageT<64, 256>(Wb + (size_t)col0 * E_ + k0, E_, Bsm);
    __syncthreads();
#pragma unroll
    for (int ks = 0; ks < 2; ks++) {
      bf16x8 af[4], bfr[2];
#pragma unroll
      for (int mi = 0; mi < 4; mi++) af[mi] = frag_ld(Asm, wr * 64 + mi * 16 + c, ks);
#pragma unroll
      for (int ni = 0; ni < 2; ni++) bfr[ni] = frag_ld(Bsm, wc * 32 + ni * 16 + c, ks);
#pragma unroll
      for (int mi = 0; mi < 4; mi++)
#pragma unroll
        for (int ni = 0; ni < 2; ni++)
          acc[mi][ni] = MFMA16(af[mi], bfr[ni], acc[mi][ni]);
    }
    __syncthreads();
  }

#pragma unroll
  for (int mi = 0; mi < 4; mi++) {
#pragma unroll
    for (int ni = 0; ni < 2; ni++) {
      const int row = row0 + wr * 64 + mi * 16 + g * 4;
      const int col = col0 + wc * 32 + ni * 16 + c;
      const float bvf = bias[col];
#pragma unroll
      for (int r = 0; r < 4; r++)
        outf[(size_t)(row + r) * E_ + col] = acc[mi][ni][r] + bvf;
    }
  }
}

// ---------------------------------------------------------------------------
// Phase A: rowsum[m] = sum_{n<=m} exp(T[m,n]) (K pre-scaled), then scales Vt
// columns m by 1/rowsum in place.  8 waves; 64-row m-blocks diagonal-paired.
// ---------------------------------------------------------------------------
__global__ __launch_bounds__(512, 4) void phaseA(
    const bf16* __restrict__ Kh, const bf16* __restrict__ Qh,
    bf16* __restrict__ Vt) {
  __shared__ char Ksm[8192];
  __shared__ char Qsm[2][16384];
  __shared__ float rbuf[2][64];
  const int t = threadIdx.x, lane = t & 63, w = t >> 6;
  const int c = lane & 15, g = (lane >> 4);
  const int wm = w & 3, wn = w >> 2;
  const int bid = blockIdx.y * 16 + blockIdx.x;   // 512 blocks
  const int ww = (bid & 7) * 64 + (bid >> 3);     // XCD-contiguous
  const int bx = ww & 15, bh = ww >> 4;
  const bf16* Kb = Kh + (size_t)bh * N_ * KD_;
  const bf16* Qb = Qh + (size_t)bh * N_ * KD_;
  bf16* Vtb = Vt + (size_t)bh * KD_ * N_;

#pragma unroll 1
  for (int seg = 0; seg < 2; seg++) {
    const int mb = seg ? (31 - bx) : bx;       // 64-row m-block
    const int m0 = mb * 64;
    const int ntE = mb >> 1;                   // last (masked) 128-wide tile

    WAITCNT("lgkmcnt(0)");
    SBAR();                                    // prior-seg LDS reads done
    stageT<64, 512>(Kb + (size_t)m0 * KD_, KD_, Ksm);          // 1 load
    stageT<128, 512>(Qb, KD_, Qsm[0]);                         // 2 loads
    WAITCNT("vmcnt(2)");                       // K landed; Q0 in flight
    SBAR();
    bf16x8 af0 = frag_ld(Ksm, wm * 16 + c, 0);
    bf16x8 af1 = frag_ld(Ksm, wm * 16 + c, 1);
    float sm[4] = {};

#pragma unroll 1
    for (int nt = 0; nt <= ntE; nt++) {
      WAITCNT("vmcnt(0) lgkmcnt(0)");
      SBAR();
      if (nt + 1 <= ntE)
        stageT<128, 512>(Qb + (size_t)(nt + 1) * 128 * KD_, KD_,
                         Qsm[(nt + 1) & 1]);
      const char* qs = Qsm[nt & 1];
      if (nt < ntE) {
#pragma unroll
        for (int nf = 0; nf < 4; nf++) {
          const int ni = wn * 4 + nf;
          bf16x8 b0 = frag_ld(qs, ni * 16 + c, 0);
          bf16x8 b1 = frag_ld(qs, ni * 16 + c, 1);
          SETPRIO(1);
          f32x4 sv = {0.f, 0.f, 0.f, 0.f};
          sv = MFMA16(af0, b0, sv);
          sv = MFMA16(af1, b1, sv);
          SETPRIO(0);
#pragma unroll
          for (int r = 0; r < 4; r++) sm[r] += exp2f(sv[r]);
        }
      } else {
        const int mg = m0 + wm * 16 + g * 4;   // m for r=0
#pragma unroll
        for (int nf = 0; nf < 4; nf++) {
          const int ni = wn * 4 + nf;
          bf16x8 b0 = frag_ld(qs, ni * 16 + c, 0);
          bf16x8 b1 = frag_ld(qs, ni * 16 + c, 1);
          SETPRIO(1);
          f32x4 sv = {0.f, 0.f, 0.f, 0.f};
          sv = MFMA16(af0, b0, sv);
          sv = MFMA16(af1, b1, sv);
          SETPRIO(0);
          const int ng = nt * 128 + ni * 16 + c;
#pragma unroll
          for (int r = 0; r < 4; r++) {
            float e = exp2f(sv[r]);
            sm[r] += (ng <= mg + r) ? e : 0.f;
          }
        }
      }
    }

#pragma unroll
    for (int r = 0; r < 4; r++) {
      float v = sm[r];
#pragma unroll
      for (int d = 1; d < 16; d <<= 1) v += __shfl_xor(v, d, 64);
      if (c == 0) rbuf[wn][wm * 16 + g * 4 + r] = v;
    }
    WAITCNT("lgkmcnt(0)");
    SBAR();                                    // rbuf visible to all
    {
      const int kd = t >> 3, mc = (t & 7) * 8;
      bf16* p = Vtb + (size_t)kd * N_ + m0 + mc;
      bf16x8 v = *(const bf16x8*)p;
      bf16x8 o;
#pragma unroll
      for (int j = 0; j < 8; j++) {
        const float inv = 1.0f / (rbuf[0][mc + j] + rbuf[1][mc + j]);
        o[j] = bf16bits(bf16f(v[j]) * inv);
      }
      *(bf16x8*)p = o;
    }
  }
}

// ---------------------------------------------------------------------------
// Phase B: out[n][kd] = sum_{m>=n} exp(T[m,n]) * V'[m][kd]  (V pre-divided by
// rowsum, K pre-scaled).  8 waves; QBLK=64, diagonal-paired (qt, 31-qt) ->
// uniform 33 m-tiles.  ONE barrier per tile via PV-lag pipeline:
//   iter mt: lgkm0+SBAR; issue K,V(mt+1); PV(mt-1) [LDS-resident];
//            vmcnt(2) [K,V(mt) landed]; QK(mt) -> P[mt&1].
// K 2-buf, V 3-buf, P 2-buf (56 KB LDS, 2 blocks/CU).  Diagonal peeled.
// QK: wave = (m-frag wm, n-half wn).  PV: wave = (n-frag wm, kd-half wn).
// ---------------------------------------------------------------------------
__global__ __launch_bounds__(512, 4) void phaseB(
    const bf16* __restrict__ Qh, const bf16* __restrict__ Kh,
    const bf16* __restrict__ Vt, bf16* __restrict__ attn) {
  __shared__ char Ksm[2][8192];
  __shared__ char Vsm[3][8192];
  __shared__ char Psm[2][8192];
  const int t = threadIdx.x, lane = t & 63, w = t >> 6;
  const int c = lane & 15, g = lane >> 4;
  const int wm = w & 3, wn = w >> 2;
  const int bid = blockIdx.y * 16 + blockIdx.x;   // 512 blocks
  const int ww = (bid & 7) * 64 + (bid >> 3);     // XCD-contiguous
  const int bx = ww & 15, bh = ww >> 4;
  const int b = bh >> 4, h = bh & 15;
  const int NT = N_ / 64;
  const bf16* Qb = Qh + (size_t)bh * N_ * KD_;
  const bf16* Kb = Kh + (size_t)bh * N_ * KD_;
  const bf16* Vb = Vt + (size_t)bh * KD_ * N_;   // rows kd, stride N_

#pragma unroll 1
  for (int seg = 0; seg < 2; seg++) {
    const int qt = seg ? (31 - bx) : bx;       // 64-row q-tile
    const int n0 = qt * 64, mt0 = qt;

    WAITCNT("lgkmcnt(0)");
    SBAR();                                    // prior-seg LDS reads done
    stageT<64, 512>(Qb + (size_t)n0 * KD_, KD_, Psm[0]);          // 1 load
    stageT<64, 512>(Kb + (size_t)mt0 * 64 * KD_, KD_, Ksm[mt0 & 1]);  // 1
    stageT<64, 512>(Vb + mt0 * 64, N_, Vsm[mt0 % 3]);                 // 1
    WAITCNT("vmcnt(2)");                       // Q landed; K/V in flight
    SBAR();
    bf16x8 qf[2][2];
#pragma unroll
    for (int ni = 0; ni < 2; ni++) {
      qf[ni][0] = frag_ld(Psm[0], wn * 32 + ni * 16 + c, 0);
      qf[ni][1] = frag_ld(Psm[0], wn * 32 + ni * 16 + c, 1);
    }
    WAITCNT("lgkmcnt(0)");
    SBAR();                                    // all waves hold qf; Psm[0] free
    f32x4 out[2] = {};

    // ---- QK for tile mt -> P[mt&1] (mask iff diag) ----
    auto qk_tile = [&](int mt, bool diag) {
      const char* ksm = Ksm[mt & 1];
      bf16x8 kf0 = frag_ld(ksm, wm * 16 + c, 0);
      bf16x8 kf1 = frag_ld(ksm, wm * 16 + c, 1);
      SETPRIO(1);
      f32x4 sv[2];
#pragma unroll
      for (int ni = 0; ni < 2; ni++) {
        f32x4 z = {0.f, 0.f, 0.f, 0.f};
        z = MFMA16(kf0, qf[ni][0], z);
        z = MFMA16(kf1, qf[ni][1], z);
        sv[ni] = z;
      }
      SETPRIO(0);
      const int ml = wm * 16 + g * 4;          // m-local for r=0
      char* ps = Psm[mt & 1];
#pragma unroll
      for (int ni = 0; ni < 2; ni++) {
        const int nl = wn * 32 + ni * 16 + c;  // P^T row (n-local)
        s16x4 p;
#pragma unroll
        for (int r = 0; r < 4; r++) {
          float val = exp2f(sv[ni][r]);
          if (diag && nl > (ml + r)) val = 0.f;
          p[r] = bf16bits(val);
        }
        const int off = nl * 128 + ((wm * 32 + g * 8) ^ ((nl & 7) << 4));
        *(s16x4*)(ps + off) = p;
      }
    };

    // ---- PV for tile mt (reads P[mt&1], V[mt%3]) ----
    auto pv_tile = [&](int mt) {
      const char* ps = Psm[mt & 1];
      const char* vsm = Vsm[mt % 3];
      bf16x8 pa0 = frag_ld(ps, wm * 16 + c, 0);
      bf16x8 pa1 = frag_ld(ps, wm * 16 + c, 1);
      SETPRIO(1);
#pragma unroll
      for (int ni = 0; ni < 2; ni++) {
        const int kdrow = wn * 32 + ni * 16 + c;
        bf16x8 v0 = frag_ld(vsm, kdrow, 0);
        bf16x8 v1 = frag_ld(vsm, kdrow, 1);
        out[ni] = MFMA16(pa0, v0, out[ni]);
        out[ni] = MFMA16(pa1, v1, out[ni]);
      }
      SETPRIO(0);
    };

    // ---- peeled diagonal tile (no PV yet) ----
    if (mt0 + 1 < NT) {
      stageT<64, 512>(Kb + (size_t)(mt0 + 1) * 64 * KD_, KD_, Ksm[(mt0 + 1) & 1]);
      stageT<64, 512>(Vb + (mt0 + 1) * 64, N_, Vsm[(mt0 + 1) % 3]);
      WAITCNT("vmcnt(2)");                     // K,V(mt0) landed
    } else {
      WAITCNT("vmcnt(0)");
    }
    qk_tile(mt0, true);

    // ---- main loop: 1 barrier per tile ----
#pragma unroll 1
    for (int mt = mt0 + 1; mt < NT; mt++) {
      WAITCNT("lgkmcnt(0)");
      SBAR();                                  // P[mt-1] visible; buffers free
      if (mt + 1 < NT) {
        stageT<64, 512>(Kb + (size_t)(mt + 1) * 64 * KD_, KD_, Ksm[(mt + 1) & 1]);
        stageT<64, 512>(Vb + (mt + 1) * 64, N_, Vsm[(mt + 1) % 3]);
      }
      pv_tile(mt - 1);                         // LDS-resident operands
      if (mt + 1 < NT) WAITCNT("vmcnt(2)");    // K,V(mt) landed
      else WAITCNT("vmcnt(0)");
      qk_tile(mt, false);
    }

    WAITCNT("lgkmcnt(0)");
    SBAR();                                    // last P tile visible
    pv_tile(NT - 1);

#pragma unroll
    for (int ni = 0; ni < 2; ni++) {
#pragma unroll
      for (int r = 0; r < 4; r++) {
        const int n = n0 + wm * 16 + g * 4 + r;
        const int kd = wn * 32 + ni * 16 + c;
        attn[((size_t)(b * N_ + n)) * E_ + h * 64 + kd] =
            __float2bfloat16(out[ni][r]);
      }
    }
  }
}

// ---------------------------------------------------------------------------
extern "C" void kernel_launch(void* const* d_in, const int* in_sizes, int n_in,
                              void* d_out, int out_size, void* d_ws, size_t ws_size,
                              hipStream_t stream) {
  (void)in_sizes; (void)n_in; (void)out_size; (void)ws_size;
  const float* x  = (const float*)d_in[0];
  const float* Wq = (const float*)d_in[1];
  const float* bq = (const float*)d_in[2];
  const float* Wk = (const float*)d_in[3];
  const float* bk = (const float*)d_in[4];
  const float* Wv = (const float*)d_in[5];
  const float* bv = (const float*)d_in[6];
  const float* Wp = (const float*)d_in[7];
  const float* bp = (const float*)d_in[8];
  float* out = (float*)d_out;

  const size_t XN = (size_t)M_ * E_;             // 4M elems
  const size_t WN = (size_t)E_ * E_;             // 1M elems
  const size_t HN = (size_t)B_ * H_ * N_ * KD_;  // 4M elems

  bf16* xb   = (bf16*)d_ws;            // reused as attn buffer later
  bf16* wqkv = xb + XN;                // wq|wk|wv contiguous = fused [3E][E]
  bf16* wpb  = wqkv + 3 * WN;
  bf16* Qhd  = wpb + WN;
  bf16* Khd  = Qhd + HN;
  bf16* Vtd  = Khd + HN;
  bf16* attn = xb;                     // xb dead after QKV GEMM

  cvt_all<<<dim3(8192), 256, 0, stream>>>(x, Wq, Wk, Wv, Wp, xb);

  gemm_qkv<<<dim3(24, 32), 256, 0, stream>>>(xb, wqkv, bq, bk, bv,
                                             Qhd, Khd, Vtd);

  phaseA<<<dim3(16, B_ * H_), 512, 0, stream>>>(Khd, Qhd, Vtd);
  phaseB<<<dim3(16, B_ * H_), 512, 0, stream>>>(Qhd, Khd, Vtd, attn);

  gemm_proj<<<dim3(16, 32), 256, 0, stream>>>(attn, wpb, bp, out);
}

// Round 19
// 110.252 us; speedup vs baseline: 1.1173x; 1.1173x over previous
//
#include <hip/hip_runtime.h>
#include <hip/hip_bf16.h>

typedef __hip_bfloat16 bf16;
typedef __attribute__((ext_vector_type(8))) short bf16x8;
typedef __attribute__((ext_vector_type(4))) float f32x4;
typedef __attribute__((ext_vector_type(4))) short s16x4;

constexpr int B_ = 2, N_ = 2048, E_ = 1024, H_ = 16, KD_ = 64;
constexpr int M_ = B_ * N_;                 // 4096 token rows
constexpr float SCALE = 0.25f * 1.44269504088896f;  // (1/4) * log2(e), folded into K

#define MFMA16(A, Bf, C) __builtin_amdgcn_mfma_f32_16x16x32_bf16(A, Bf, C, 0, 0, 0)
#define SBAR() do { __builtin_amdgcn_s_barrier(); __builtin_amdgcn_sched_barrier(0); } while (0)
#define WAITCNT(s) asm volatile("s_waitcnt " s ::: "memory")
#define SETPRIO(p) __builtin_amdgcn_s_setprio(p)

typedef const __attribute__((address_space(1))) void* gptr_t;
typedef __attribute__((address_space(3))) void* sptr_t;

__device__ inline short bf16bits(float f) {
  bf16 h = __float2bfloat16(f);
  short s;
  __builtin_memcpy(&s, &h, 2);
  return s;
}
__device__ inline float bf16f(short s) {
  bf16 h;
  __builtin_memcpy(&h, &s, 2);
  return __bfloat162float(h);
}
// COMPILER-VISIBLE raw v_exp_f32 (not inline asm -- the hazard recognizer
// handles the TRANS-pipe result hazard, which the r17 asm version did not).
// Args here are bounded (|x| <~ 12), inside the range where OCML exp2f ==
// v_exp_f32 exactly; skips OCML's ~4-op denormal guard.
__device__ inline float fexp2(float x) { return __builtin_amdgcn_exp2f(x); }

// ---------------------------------------------------------------------------
// Stage NROWS x 128 bytes global->LDS with the XOR swizzle
// (logical (row,slot16) at byte row*128 + ((slot*16) ^ ((row&7)<<4))).
// Pre-swizzled SOURCE + linear global_load_lds dest (rule #21).
// ---------------------------------------------------------------------------
template <int NROWS, int NTHR>
__device__ inline void stageT(const bf16* __restrict__ base, int stride_elems,
                              char* lds) {
  const int t = threadIdx.x;
#pragma unroll
  for (int i = 0; i < NROWS * 128 / (NTHR * 16); i++) {
    int L = i * NTHR * 16 + t * 16;               // linear LDS byte offset
    int row = L >> 7;
    int slot = ((L >> 4) & 7) ^ (row & 7);        // inverse of the XOR swizzle
    const bf16* src = base + (size_t)row * stride_elems + slot * 8;
    __builtin_amdgcn_global_load_lds((gptr_t)(const void*)src,
                                     (sptr_t)(void*)(lds + L), 16, 0, 0);
  }
}

// Read one MFMA A/B fragment (8 bf16 along k) from a swizzled tile (128B rows).
__device__ inline bf16x8 frag_ld(const char* lds, int row, int ks) {
  const int g = (threadIdx.x >> 4) & 3;           // lane>>4 within wave
  const int off = (ks * 64 + g * 16) ^ ((row & 7) << 4);
  return *(const bf16x8*)(lds + row * 128 + off);
}

// ---------------------------------------------------------------------------
// Elementwise fp32 -> bf16 for x, Wq, Wk, Wv, Wp (contiguous dst).
// ---------------------------------------------------------------------------
__global__ __launch_bounds__(256) void cvt_all(
    const float* __restrict__ x, const float* __restrict__ wq,
    const float* __restrict__ wk, const float* __restrict__ wv,
    const float* __restrict__ wp, bf16* __restrict__ dst) {
  const size_t XN = (size_t)M_ * E_;              // 4M
  const size_t WN = (size_t)E_ * E_;              // 1M
  size_t i = ((size_t)blockIdx.x * 256 + threadIdx.x) * 4;
  const float* src;
  size_t off;
  if (i < XN) { src = x; off = i; }
  else if (i < XN + WN) { src = wq; off = i - XN; }
  else if (i < XN + 2 * WN) { src = wk; off = i - XN - WN; }
  else if (i < XN + 3 * WN) { src = wv; off = i - XN - 2 * WN; }
  else { src = wp; off = i - XN - 3 * WN; }
  float4 v = *(const float4*)(src + off);
  s16x4 o;
  o[0] = bf16bits(v.x); o[1] = bf16bits(v.y);
  o[2] = bf16bits(v.z); o[3] = bf16bits(v.w);
  *(s16x4*)(dst + i) = o;
}

// ---------------------------------------------------------------------------
// Fused QKV GEMM: [Q|K|V] = x @ Wqkv^T + b.  128x128 tile, BK=64, 4 waves.
// Q head-major; K head-major PRE-SCALED by (1/4)*log2(e); V transposed heads.
// ---------------------------------------------------------------------------
__global__ __launch_bounds__(256) void gemm_qkv(
    const bf16* __restrict__ A, const bf16* __restrict__ Wb,
    const float* __restrict__ bq, const float* __restrict__ bk,
    const float* __restrict__ bv, bf16* __restrict__ Qhd,
    bf16* __restrict__ Khd, bf16* __restrict__ Vtd) {
  __shared__ char Asm[16384];
  __shared__ char Bsm[16384];
  const int t = threadIdx.x, lane = t & 63, w = t >> 6;
  const int wr = w >> 1, wc = w & 1;
  const int c = lane & 15, g = lane >> 4;
  const int row0 = blockIdx.y * 128, col0 = blockIdx.x * 128;
  f32x4 acc[4][4] = {};

  for (int k0 = 0; k0 < E_; k0 += 64) {
    stageT<64, 256>(A + (size_t)row0 * E_ + k0, E_, Asm);
    stageT<64, 256>(A + (size_t)(row0 + 64) * E_ + k0, E_, Asm + 8192);
    stageT<64, 256>(Wb + (size_t)col0 * E_ + k0, E_, Bsm);
    stageT<64, 256>(Wb + (size_t)(col0 + 64) * E_ + k0, E_, Bsm + 8192);
    __syncthreads();
#pragma unroll
    for (int ks = 0; ks < 2; ks++) {
      bf16x8 af[4], bfr[4];
#pragma unroll
      for (int mi = 0; mi < 4; mi++) af[mi] = frag_ld(Asm, wr * 64 + mi * 16 + c, ks);
#pragma unroll
      for (int ni = 0; ni < 4; ni++) bfr[ni] = frag_ld(Bsm, wc * 64 + ni * 16 + c, ks);
#pragma unroll
      for (int mi = 0; mi < 4; mi++)
#pragma unroll
        for (int ni = 0; ni < 4; ni++)
          acc[mi][ni] = MFMA16(af[mi], bfr[ni], acc[mi][ni]);
    }
    __syncthreads();
  }

  const int sel = col0 >> 10;                     // 0:Q 1:K 2:V (uniform)
  const float* biasp = sel == 0 ? bq : sel == 1 ? bk : bv;
  bf16* outp = sel == 0 ? Qhd : sel == 1 ? Khd : Vtd;
#pragma unroll
  for (int mi = 0; mi < 4; mi++) {
#pragma unroll
    for (int ni = 0; ni < 4; ni++) {
      const int row = row0 + wr * 64 + mi * 16 + g * 4;
      const int col = col0 + wc * 64 + ni * 16 + c;
      const int ccol = col & 1023, h = ccol >> 6, kd = ccol & 63;
      const float bvf = biasp[ccol];
      if (sel < 2) {
        const float scl = (sel == 1) ? SCALE : 1.0f;
#pragma unroll
        for (int r = 0; r < 4; r++) {
          const int rr = row + r, b = rr >> 11, n = rr & (N_ - 1);
          outp[(((size_t)(b * H_ + h)) * N_ + n) * KD_ + kd] =
              __float2bfloat16((acc[mi][ni][r] + bvf) * scl);
        }
      } else {
        const int b = row >> 11, n = row & (N_ - 1);
        s16x4 o;
#pragma unroll
        for (int r = 0; r < 4; r++) o[r] = bf16bits(acc[mi][ni][r] + bvf);
        *(s16x4*)&outp[(((size_t)(b * H_ + h)) * KD_ + kd) * N_ + n] = o;
      }
    }
  }
}

// ---------------------------------------------------------------------------
// Projection GEMM: out(fp32) = attn @ Wp^T + bp.  128x64 tile -> 512 blocks.
// ---------------------------------------------------------------------------
__global__ __launch_bounds__(256) void gemm_proj(
    const bf16* __restrict__ A, const bf16* __restrict__ Wb,
    const float* __restrict__ bias, float* __restrict__ outf) {
  __shared__ char Asm[16384];
  __shared__ char Bsm[8192];
  const int t = threadIdx.x, lane = t & 63, w = t >> 6;
  const int wr = w >> 1, wc = w & 1;
  const int c = lane & 15, g = lane >> 4;
  const int row0 = blockIdx.y * 128, col0 = blockIdx.x * 64;
  f32x4 acc[4][2] = {};

  for (int k0 = 0; k0 < E_; k0 += 64) {
    stageT<64, 256>(A + (size_t)row0 * E_ + k0, E_, Asm);
    stageT<64, 256>(A + (size_t)(row0 + 64) * E_ + k0, E_, Asm + 8192);
    stageT<64, 256>(Wb + (size_t)col0 * E_ + k0, E_, Bsm);
    __syncthreads();
#pragma unroll
    for (int ks = 0; ks < 2; ks++) {
      bf16x8 af[4], bfr[2];
#pragma unroll
      for (int mi = 0; mi < 4; mi++) af[mi] = frag_ld(Asm, wr * 64 + mi * 16 + c, ks);
#pragma unroll
      for (int ni = 0; ni < 2; ni++) bfr[ni] = frag_ld(Bsm, wc * 32 + ni * 16 + c, ks);
#pragma unroll
      for (int mi = 0; mi < 4; mi++)
#pragma unroll
        for (int ni = 0; ni < 2; ni++)
          acc[mi][ni] = MFMA16(af[mi], bfr[ni], acc[mi][ni]);
    }
    __syncthreads();
  }

#pragma unroll
  for (int mi = 0; mi < 4; mi++) {
#pragma unroll
    for (int ni = 0; ni < 2; ni++) {
      const int row = row0 + wr * 64 + mi * 16 + g * 4;
      const int col = col0 + wc * 32 + ni * 16 + c;
      const float bvf = bias[col];
#pragma unroll
      for (int r = 0; r < 4; r++)
        outf[(size_t)(row + r) * E_ + col] = acc[mi][ni][r] + bvf;
    }
  }
}

// ---------------------------------------------------------------------------
// Phase A: rowsum[m] = sum_{n<=m} exp(T[m,n]) (K pre-scaled), then scales Vt
// columns m by 1/rowsum in place.  8 waves; 64-row m-blocks diagonal-paired.
// ---------------------------------------------------------------------------
__global__ __launch_bounds__(512, 4) void phaseA(
    const bf16* __restrict__ Kh, const bf16* __restrict__ Qh,
    bf16* __restrict__ Vt) {
  __shared__ char Ksm[8192];
  __shared__ char Qsm[2][16384];
  __shared__ float rbuf[2][64];
  const int t = threadIdx.x, lane = t & 63, w = t >> 6;
  const int c = lane & 15, g = (lane >> 4);
  const int wm = w & 3, wn = w >> 2;
  const int bid = blockIdx.y * 16 + blockIdx.x;   // 512 blocks
  const int ww = (bid & 7) * 64 + (bid >> 3);     // XCD-contiguous
  const int bx = ww & 15, bh = ww >> 4;
  const bf16* Kb = Kh + (size_t)bh * N_ * KD_;
  const bf16* Qb = Qh + (size_t)bh * N_ * KD_;
  bf16* Vtb = Vt + (size_t)bh * KD_ * N_;

#pragma unroll 1
  for (int seg = 0; seg < 2; seg++) {
    const int mb = seg ? (31 - bx) : bx;       // 64-row m-block
    const int m0 = mb * 64;
    const int ntE = mb >> 1;                   // last (masked) 128-wide tile

    WAITCNT("lgkmcnt(0)");
    SBAR();                                    // prior-seg LDS reads done
    stageT<64, 512>(Kb + (size_t)m0 * KD_, KD_, Ksm);          // 1 load
    stageT<128, 512>(Qb, KD_, Qsm[0]);                         // 2 loads
    WAITCNT("vmcnt(2)");                       // K landed; Q0 in flight
    SBAR();
    bf16x8 af0 = frag_ld(Ksm, wm * 16 + c, 0);
    bf16x8 af1 = frag_ld(Ksm, wm * 16 + c, 1);
    float sm[4] = {};

#pragma unroll 1
    for (int nt = 0; nt <= ntE; nt++) {
      WAITCNT("vmcnt(0) lgkmcnt(0)");
      SBAR();
      if (nt + 1 <= ntE)
        stageT<128, 512>(Qb + (size_t)(nt + 1) * 128 * KD_, KD_,
                         Qsm[(nt + 1) & 1]);
      const char* qs = Qsm[nt & 1];
      if (nt < ntE) {
#pragma unroll
        for (int nf = 0; nf < 4; nf++) {
          const int ni = wn * 4 + nf;
          bf16x8 b0 = frag_ld(qs, ni * 16 + c, 0);
          bf16x8 b1 = frag_ld(qs, ni * 16 + c, 1);
          SETPRIO(1);
          f32x4 sv = {0.f, 0.f, 0.f, 0.f};
          sv = MFMA16(af0, b0, sv);
          sv = MFMA16(af1, b1, sv);
          SETPRIO(0);
#pragma unroll
          for (int r = 0; r < 4; r++) sm[r] += fexp2(sv[r]);
        }
      } else {
        const int mg = m0 + wm * 16 + g * 4;   // m for r=0
#pragma unroll
        for (int nf = 0; nf < 4; nf++) {
          const int ni = wn * 4 + nf;
          bf16x8 b0 = frag_ld(qs, ni * 16 + c, 0);
          bf16x8 b1 = frag_ld(qs, ni * 16 + c, 1);
          SETPRIO(1);
          f32x4 sv = {0.f, 0.f, 0.f, 0.f};
          sv = MFMA16(af0, b0, sv);
          sv = MFMA16(af1, b1, sv);
          SETPRIO(0);
          const int ng = nt * 128 + ni * 16 + c;
#pragma unroll
          for (int r = 0; r < 4; r++) {
            float e = fexp2(sv[r]);
            sm[r] += (ng <= mg + r) ? e : 0.f;
          }
        }
      }
    }

#pragma unroll
    for (int r = 0; r < 4; r++) {
      float v = sm[r];
#pragma unroll
      for (int d = 1; d < 16; d <<= 1) v += __shfl_xor(v, d, 64);
      if (c == 0) rbuf[wn][wm * 16 + g * 4 + r] = v;
    }
    WAITCNT("lgkmcnt(0)");
    SBAR();                                    // rbuf visible to all
    {
      const int kd = t >> 3, mc = (t & 7) * 8;
      bf16* p = Vtb + (size_t)kd * N_ + m0 + mc;
      bf16x8 v = *(const bf16x8*)p;
      bf16x8 o;
#pragma unroll
      for (int j = 0; j < 8; j++) {
        const float inv = 1.0f / (rbuf[0][mc + j] + rbuf[1][mc + j]);
        o[j] = bf16bits(bf16f(v[j]) * inv);
      }
      *(bf16x8*)p = o;
    }
  }
}

// ---------------------------------------------------------------------------
// Phase B: out[n][kd] = sum_{m>=n} exp(T[m,n]) * V'[m][kd]  (V pre-divided by
// rowsum, K pre-scaled).  8 waves; QBLK=64, diagonal-paired (qt, 31-qt) ->
// uniform 33 m-tiles.  ONE barrier per tile via PV-lag pipeline:
//   iter mt: lgkm0+SBAR; issue K,V(mt+1); PV(mt-1) [LDS-resident];
//            vmcnt(2) [K,V(mt) landed]; QK(mt) -> P[mt&1].
// K 2-buf, V 3-buf, P 2-buf (56 KB LDS, 2 blocks/CU).  Diagonal peeled.
// QK: wave = (m-frag wm, n-half wn).  PV: wave = (n-frag wm, kd-half wn).
// ---------------------------------------------------------------------------
__global__ __launch_bounds__(512, 4) void phaseB(
    const bf16* __restrict__ Qh, const bf16* __restrict__ Kh,
    const bf16* __restrict__ Vt, bf16* __restrict__ attn) {
  __shared__ char Ksm[2][8192];
  __shared__ char Vsm[3][8192];
  __shared__ char Psm[2][8192];
  const int t = threadIdx.x, lane = t & 63, w = t >> 6;
  const int c = lane & 15, g = lane >> 4;
  const int wm = w & 3, wn = w >> 2;
  const int bid = blockIdx.y * 16 + blockIdx.x;   // 512 blocks
  const int ww = (bid & 7) * 64 + (bid >> 3);     // XCD-contiguous
  const int bx = ww & 15, bh = ww >> 4;
  const int b = bh >> 4, h = bh & 15;
  const int NT = N_ / 64;
  const bf16* Qb = Qh + (size_t)bh * N_ * KD_;
  const bf16* Kb = Kh + (size_t)bh * N_ * KD_;
  const bf16* Vb = Vt + (size_t)bh * KD_ * N_;   // rows kd, stride N_

#pragma unroll 1
  for (int seg = 0; seg < 2; seg++) {
    const int qt = seg ? (31 - bx) : bx;       // 64-row q-tile
    const int n0 = qt * 64, mt0 = qt;

    WAITCNT("lgkmcnt(0)");
    SBAR();                                    // prior-seg LDS reads done
    stageT<64, 512>(Qb + (size_t)n0 * KD_, KD_, Psm[0]);          // 1 load
    stageT<64, 512>(Kb + (size_t)mt0 * 64 * KD_, KD_, Ksm[mt0 & 1]);  // 1
    stageT<64, 512>(Vb + mt0 * 64, N_, Vsm[mt0 % 3]);                 // 1
    WAITCNT("vmcnt(2)");                       // Q landed; K/V in flight
    SBAR();
    bf16x8 qf[2][2];
#pragma unroll
    for (int ni = 0; ni < 2; ni++) {
      qf[ni][0] = frag_ld(Psm[0], wn * 32 + ni * 16 + c, 0);
      qf[ni][1] = frag_ld(Psm[0], wn * 32 + ni * 16 + c, 1);
    }
    WAITCNT("lgkmcnt(0)");
    SBAR();                                    // all waves hold qf; Psm[0] free
    f32x4 out[2] = {};

    // ---- QK for tile mt -> P[mt&1] (mask iff diag) ----
    auto qk_tile = [&](int mt, bool diag) {
      const char* ksm = Ksm[mt & 1];
      bf16x8 kf0 = frag_ld(ksm, wm * 16 + c, 0);
      bf16x8 kf1 = frag_ld(ksm, wm * 16 + c, 1);
      SETPRIO(1);
      f32x4 sv[2];
#pragma unroll
      for (int ni = 0; ni < 2; ni++) {
        f32x4 z = {0.f, 0.f, 0.f, 0.f};
        z = MFMA16(kf0, qf[ni][0], z);
        z = MFMA16(kf1, qf[ni][1], z);
        sv[ni] = z;
      }
      SETPRIO(0);
      const int ml = wm * 16 + g * 4;          // m-local for r=0
      char* ps = Psm[mt & 1];
#pragma unroll
      for (int ni = 0; ni < 2; ni++) {
        const int nl = wn * 32 + ni * 16 + c;  // P^T row (n-local)
        s16x4 p;
#pragma unroll
        for (int r = 0; r < 4; r++) {
          float val = fexp2(sv[ni][r]);
          if (diag && nl > (ml + r)) val = 0.f;
          p[r] = bf16bits(val);
        }
        const int off = nl * 128 + ((wm * 32 + g * 8) ^ ((nl & 7) << 4));
        *(s16x4*)(ps + off) = p;
      }
    };

    // ---- PV for tile mt (reads P[mt&1], V[mt%3]) ----
    auto pv_tile = [&](int mt) {
      const char* ps = Psm[mt & 1];
      const char* vsm = Vsm[mt % 3];
      bf16x8 pa0 = frag_ld(ps, wm * 16 + c, 0);
      bf16x8 pa1 = frag_ld(ps, wm * 16 + c, 1);
      SETPRIO(1);
#pragma unroll
      for (int ni = 0; ni < 2; ni++) {
        const int kdrow = wn * 32 + ni * 16 + c;
        bf16x8 v0 = frag_ld(vsm, kdrow, 0);
        bf16x8 v1 = frag_ld(vsm, kdrow, 1);
        out[ni] = MFMA16(pa0, v0, out[ni]);
        out[ni] = MFMA16(pa1, v1, out[ni]);
      }
      SETPRIO(0);
    };

    // ---- peeled diagonal tile (no PV yet) ----
    if (mt0 + 1 < NT) {
      stageT<64, 512>(Kb + (size_t)(mt0 + 1) * 64 * KD_, KD_, Ksm[(mt0 + 1) & 1]);
      stageT<64, 512>(Vb + (mt0 + 1) * 64, N_, Vsm[(mt0 + 1) % 3]);
      WAITCNT("vmcnt(2)");                     // K,V(mt0) landed
    } else {
      WAITCNT("vmcnt(0)");
    }
    qk_tile(mt0, true);

    // ---- main loop: 1 barrier per tile ----
#pragma unroll 1
    for (int mt = mt0 + 1; mt < NT; mt++) {
      WAITCNT("lgkmcnt(0)");
      SBAR();                                  // P[mt-1] visible; buffers free
      if (mt + 1 < NT) {
        stageT<64, 512>(Kb + (size_t)(mt + 1) * 64 * KD_, KD_, Ksm[(mt + 1) & 1]);
        stageT<64, 512>(Vb + (mt + 1) * 64, N_, Vsm[(mt + 1) % 3]);
      }
      pv_tile(mt - 1);                         // LDS-resident operands
      if (mt + 1 < NT) WAITCNT("vmcnt(2)");    // K,V(mt) landed
      else WAITCNT("vmcnt(0)");
      qk_tile(mt, false);
    }

    WAITCNT("lgkmcnt(0)");
    SBAR();                                    // last P tile visible
    pv_tile(NT - 1);

#pragma unroll
    for (int ni = 0; ni < 2; ni++) {
#pragma unroll
      for (int r = 0; r < 4; r++) {
        const int n = n0 + wm * 16 + g * 4 + r;
        const int kd = wn * 32 + ni * 16 + c;
        attn[((size_t)(b * N_ + n)) * E_ + h * 64 + kd] =
            __float2bfloat16(out[ni][r]);
      }
    }
  }
}

// ---------------------------------------------------------------------------
extern "C" void kernel_launch(void* const* d_in, const int* in_sizes, int n_in,
                              void* d_out, int out_size, void* d_ws, size_t ws_size,
                              hipStream_t stream) {
  (void)in_sizes; (void)n_in; (void)out_size; (void)ws_size;
  const float* x  = (const float*)d_in[0];
  const float* Wq = (const float*)d_in[1];
  const float* bq = (const float*)d_in[2];
  const float* Wk = (const float*)d_in[3];
  const float* bk = (const float*)d_in[4];
  const float* Wv = (const float*)d_in[5];
  const float* bv = (const float*)d_in[6];
  const float* Wp = (const float*)d_in[7];
  const float* bp = (const float*)d_in[8];
  float* out = (float*)d_out;

  const size_t XN = (size_t)M_ * E_;             // 4M elems
  const size_t WN = (size_t)E_ * E_;             // 1M elems
  const size_t HN = (size_t)B_ * H_ * N_ * KD_;  // 4M elems

  bf16* xb   = (bf16*)d_ws;            // reused as attn buffer later
  bf16* wqkv = xb + XN;                // wq|wk|wv contiguous = fused [3E][E]
  bf16* wpb  = wqkv + 3 * WN;
  bf16* Qhd  = wpb + WN;
  bf16* Khd  = Qhd + HN;
  bf16* Vtd  = Khd + HN;
  bf16* attn = xb;                     // xb dead after QKV GEMM

  cvt_all<<<dim3(8192), 256, 0, stream>>>(x, Wq, Wk, Wv, Wp, xb);

  gemm_qkv<<<dim3(24, 32), 256, 0, stream>>>(xb, wqkv, bq, bk, bv,
                                             Qhd, Khd, Vtd);

  phaseA<<<dim3(16, B_ * H_), 512, 0, stream>>>(Khd, Qhd, Vtd);
  phaseB<<<dim3(16, B_ * H_), 512, 0, stream>>>(Qhd, Khd, Vtd, attn);

  gemm_proj<<<dim3(16, 32), 256, 0, stream>>>(attn, wpb, bp, out);
}

// Round 20
// 109.883 us; speedup vs baseline: 1.1210x; 1.0034x over previous
//
#include <hip/hip_runtime.h>
#include <hip/hip_bf16.h>

typedef __hip_bfloat16 bf16;
typedef __attribute__((ext_vector_type(8))) short bf16x8;
typedef __attribute__((ext_vector_type(4))) float f32x4;
typedef __attribute__((ext_vector_type(4))) short s16x4;

constexpr int B_ = 2, N_ = 2048, E_ = 1024, H_ = 16, KD_ = 64;
constexpr int M_ = B_ * N_;                 // 4096 token rows
constexpr float SCALE = 0.25f * 1.44269504088896f;  // (1/4) * log2(e), folded into K

#define MFMA16(A, Bf, C) __builtin_amdgcn_mfma_f32_16x16x32_bf16(A, Bf, C, 0, 0, 0)
#define SBAR() do { __builtin_amdgcn_s_barrier(); __builtin_amdgcn_sched_barrier(0); } while (0)
#define WAITCNT(s) asm volatile("s_waitcnt " s ::: "memory")
#define SETPRIO(p) __builtin_amdgcn_s_setprio(p)

typedef const __attribute__((address_space(1))) void* gptr_t;
typedef __attribute__((address_space(3))) void* sptr_t;

__device__ inline short bf16bits(float f) {
  bf16 h = __float2bfloat16(f);
  short s;
  __builtin_memcpy(&s, &h, 2);
  return s;
}
__device__ inline float bf16f(short s) {
  bf16 h;
  __builtin_memcpy(&h, &s, 2);
  return __bfloat162float(h);
}
// COMPILER-VISIBLE raw v_exp_f32 (not inline asm -- the hazard recognizer
// handles the TRANS-pipe result hazard, which the r17 asm version did not).
// Args here are bounded (|x| <~ 12), inside the range where OCML exp2f ==
// v_exp_f32 exactly; skips OCML's ~4-op denormal guard.
__device__ inline float fexp2(float x) { return __builtin_amdgcn_exp2f(x); }

// ---------------------------------------------------------------------------
// Stage NROWS x 128 bytes global->LDS with the XOR swizzle
// (logical (row,slot16) at byte row*128 + ((slot*16) ^ ((row&7)<<4))).
// Pre-swizzled SOURCE + linear global_load_lds dest (rule #21).
// ---------------------------------------------------------------------------
template <int NROWS, int NTHR>
__device__ inline void stageT(const bf16* __restrict__ base, int stride_elems,
                              char* lds) {
  const int t = threadIdx.x;
#pragma unroll
  for (int i = 0; i < NROWS * 128 / (NTHR * 16); i++) {
    int L = i * NTHR * 16 + t * 16;               // linear LDS byte offset
    int row = L >> 7;
    int slot = ((L >> 4) & 7) ^ (row & 7);        // inverse of the XOR swizzle
    const bf16* src = base + (size_t)row * stride_elems + slot * 8;
    __builtin_amdgcn_global_load_lds((gptr_t)(const void*)src,
                                     (sptr_t)(void*)(lds + L), 16, 0, 0);
  }
}

// Read one MFMA A/B fragment (8 bf16 along k) from a swizzled tile (128B rows).
__device__ inline bf16x8 frag_ld(const char* lds, int row, int ks) {
  const int g = (threadIdx.x >> 4) & 3;           // lane>>4 within wave
  const int off = (ks * 64 + g * 16) ^ ((row & 7) << 4);
  return *(const bf16x8*)(lds + row * 128 + off);
}

// ---------------------------------------------------------------------------
// Elementwise fp32 -> bf16 for x, Wq, Wk, Wv, Wp (contiguous dst).
// ---------------------------------------------------------------------------
__global__ __launch_bounds__(256) void cvt_all(
    const float* __restrict__ x, const float* __restrict__ wq,
    const float* __restrict__ wk, const float* __restrict__ wv,
    const float* __restrict__ wp, bf16* __restrict__ dst) {
  const size_t XN = (size_t)M_ * E_;              // 4M
  const size_t WN = (size_t)E_ * E_;              // 1M
  size_t i = ((size_t)blockIdx.x * 256 + threadIdx.x) * 4;
  const float* src;
  size_t off;
  if (i < XN) { src = x; off = i; }
  else if (i < XN + WN) { src = wq; off = i - XN; }
  else if (i < XN + 2 * WN) { src = wk; off = i - XN - WN; }
  else if (i < XN + 3 * WN) { src = wv; off = i - XN - 2 * WN; }
  else { src = wp; off = i - XN - 3 * WN; }
  float4 v = *(const float4*)(src + off);
  s16x4 o;
  o[0] = bf16bits(v.x); o[1] = bf16bits(v.y);
  o[2] = bf16bits(v.z); o[3] = bf16bits(v.w);
  *(s16x4*)(dst + i) = o;
}

// ---------------------------------------------------------------------------
// Fused QKV GEMM: [Q|K|V] = x @ Wqkv^T + b.  128x128 tile, BK=64, 4 waves.
// Q head-major; K head-major PRE-SCALED by (1/4)*log2(e); V transposed heads.
// ---------------------------------------------------------------------------
__global__ __launch_bounds__(256) void gemm_qkv(
    const bf16* __restrict__ A, const bf16* __restrict__ Wb,
    const float* __restrict__ bq, const float* __restrict__ bk,
    const float* __restrict__ bv, bf16* __restrict__ Qhd,
    bf16* __restrict__ Khd, bf16* __restrict__ Vtd) {
  __shared__ char Asm[16384];
  __shared__ char Bsm[16384];
  const int t = threadIdx.x, lane = t & 63, w = t >> 6;
  const int wr = w >> 1, wc = w & 1;
  const int c = lane & 15, g = lane >> 4;
  const int row0 = blockIdx.y * 128, col0 = blockIdx.x * 128;
  f32x4 acc[4][4] = {};

  for (int k0 = 0; k0 < E_; k0 += 64) {
    stageT<64, 256>(A + (size_t)row0 * E_ + k0, E_, Asm);
    stageT<64, 256>(A + (size_t)(row0 + 64) * E_ + k0, E_, Asm + 8192);
    stageT<64, 256>(Wb + (size_t)col0 * E_ + k0, E_, Bsm);
    stageT<64, 256>(Wb + (size_t)(col0 + 64) * E_ + k0, E_, Bsm + 8192);
    __syncthreads();
#pragma unroll
    for (int ks = 0; ks < 2; ks++) {
      bf16x8 af[4], bfr[4];
#pragma unroll
      for (int mi = 0; mi < 4; mi++) af[mi] = frag_ld(Asm, wr * 64 + mi * 16 + c, ks);
#pragma unroll
      for (int ni = 0; ni < 4; ni++) bfr[ni] = frag_ld(Bsm, wc * 64 + ni * 16 + c, ks);
#pragma unroll
      for (int mi = 0; mi < 4; mi++)
#pragma unroll
        for (int ni = 0; ni < 4; ni++)
          acc[mi][ni] = MFMA16(af[mi], bfr[ni], acc[mi][ni]);
    }
    __syncthreads();
  }

  const int sel = col0 >> 10;                     // 0:Q 1:K 2:V (uniform)
  const float* biasp = sel == 0 ? bq : sel == 1 ? bk : bv;
  bf16* outp = sel == 0 ? Qhd : sel == 1 ? Khd : Vtd;
#pragma unroll
  for (int mi = 0; mi < 4; mi++) {
#pragma unroll
    for (int ni = 0; ni < 4; ni++) {
      const int row = row0 + wr * 64 + mi * 16 + g * 4;
      const int col = col0 + wc * 64 + ni * 16 + c;
      const int ccol = col & 1023, h = ccol >> 6, kd = ccol & 63;
      const float bvf = biasp[ccol];
      if (sel < 2) {
        const float scl = (sel == 1) ? SCALE : 1.0f;
#pragma unroll
        for (int r = 0; r < 4; r++) {
          const int rr = row + r, b = rr >> 11, n = rr & (N_ - 1);
          outp[(((size_t)(b * H_ + h)) * N_ + n) * KD_ + kd] =
              __float2bfloat16((acc[mi][ni][r] + bvf) * scl);
        }
      } else {
        const int b = row >> 11, n = row & (N_ - 1);
        s16x4 o;
#pragma unroll
        for (int r = 0; r < 4; r++) o[r] = bf16bits(acc[mi][ni][r] + bvf);
        *(s16x4*)&outp[(((size_t)(b * H_ + h)) * KD_ + kd) * N_ + n] = o;
      }
    }
  }
}

// ---------------------------------------------------------------------------
// Projection GEMM: out(fp32) = attn @ Wp^T + bp.  128x64 tile -> 512 blocks.
// ---------------------------------------------------------------------------
__global__ __launch_bounds__(256) void gemm_proj(
    const bf16* __restrict__ A, const bf16* __restrict__ Wb,
    const float* __restrict__ bias, float* __restrict__ outf) {
  __shared__ char Asm[16384];
  __shared__ char Bsm[8192];
  const int t = threadIdx.x, lane = t & 63, w = t >> 6;
  const int wr = w >> 1, wc = w & 1;
  const int c = lane & 15, g = lane >> 4;
  const int row0 = blockIdx.y * 128, col0 = blockIdx.x * 64;
  f32x4 acc[4][2] = {};

  for (int k0 = 0; k0 < E_; k0 += 64) {
    stageT<64, 256>(A + (size_t)row0 * E_ + k0, E_, Asm);
    stageT<64, 256>(A + (size_t)(row0 + 64) * E_ + k0, E_, Asm + 8192);
    stageT<64, 256>(Wb + (size_t)col0 * E_ + k0, E_, Bsm);
    __syncthreads();
#pragma unroll
    for (int ks = 0; ks < 2; ks++) {
      bf16x8 af[4], bfr[2];
#pragma unroll
      for (int mi = 0; mi < 4; mi++) af[mi] = frag_ld(Asm, wr * 64 + mi * 16 + c, ks);
#pragma unroll
      for (int ni = 0; ni < 2; ni++) bfr[ni] = frag_ld(Bsm, wc * 32 + ni * 16 + c, ks);
#pragma unroll
      for (int mi = 0; mi < 4; mi++)
#pragma unroll
        for (int ni = 0; ni < 2; ni++)
          acc[mi][ni] = MFMA16(af[mi], bfr[ni], acc[mi][ni]);
    }
    __syncthreads();
  }

#pragma unroll
  for (int mi = 0; mi < 4; mi++) {
#pragma unroll
    for (int ni = 0; ni < 2; ni++) {
      const int row = row0 + wr * 64 + mi * 16 + g * 4;
      const int col = col0 + wc * 32 + ni * 16 + c;
      const float bvf = bias[col];
#pragma unroll
      for (int r = 0; r < 4; r++)
        outf[(size_t)(row + r) * E_ + col] = acc[mi][ni][r] + bvf;
    }
  }
}

// ---------------------------------------------------------------------------
// Phase A: rowsum[m] = sum_{n<=m} exp(T[m,n]) (K pre-scaled), then scales Vt
// columns m by 1/rowsum in place.  8 waves; 64-row m-blocks diagonal-paired.
// ---------------------------------------------------------------------------
__global__ __launch_bounds__(512, 4) void phaseA(
    const bf16* __restrict__ Kh, const bf16* __restrict__ Qh,
    bf16* __restrict__ Vt) {
  __shared__ char Ksm[8192];
  __shared__ char Qsm[2][16384];
  __shared__ float rbuf[2][64];
  const int t = threadIdx.x, lane = t & 63, w = t >> 6;
  const int c = lane & 15, g = (lane >> 4);
  const int wm = w & 3, wn = w >> 2;
  const int bid = blockIdx.y * 16 + blockIdx.x;   // 512 blocks
  const int ww = (bid & 7) * 64 + (bid >> 3);     // XCD-contiguous
  const int bx = ww & 15, bh = ww >> 4;
  const bf16* Kb = Kh + (size_t)bh * N_ * KD_;
  const bf16* Qb = Qh + (size_t)bh * N_ * KD_;
  bf16* Vtb = Vt + (size_t)bh * KD_ * N_;

#pragma unroll 1
  for (int seg = 0; seg < 2; seg++) {
    const int mb = seg ? (31 - bx) : bx;       // 64-row m-block
    const int m0 = mb * 64;
    const int ntE = mb >> 1;                   // last (masked) 128-wide tile

    WAITCNT("lgkmcnt(0)");
    SBAR();                                    // prior-seg LDS reads done
    stageT<64, 512>(Kb + (size_t)m0 * KD_, KD_, Ksm);          // 1 load
    stageT<128, 512>(Qb, KD_, Qsm[0]);                         // 2 loads
    WAITCNT("vmcnt(2)");                       // K landed; Q0 in flight
    SBAR();
    bf16x8 af0 = frag_ld(Ksm, wm * 16 + c, 0);
    bf16x8 af1 = frag_ld(Ksm, wm * 16 + c, 1);
    float sm[4] = {};

#pragma unroll 1
    for (int nt = 0; nt <= ntE; nt++) {
      WAITCNT("vmcnt(0) lgkmcnt(0)");
      SBAR();
      if (nt + 1 <= ntE)
        stageT<128, 512>(Qb + (size_t)(nt + 1) * 128 * KD_, KD_,
                         Qsm[(nt + 1) & 1]);
      const char* qs = Qsm[nt & 1];
      if (nt < ntE) {
#pragma unroll
        for (int nf = 0; nf < 4; nf++) {
          const int ni = wn * 4 + nf;
          bf16x8 b0 = frag_ld(qs, ni * 16 + c, 0);
          bf16x8 b1 = frag_ld(qs, ni * 16 + c, 1);
          SETPRIO(1);
          f32x4 sv = {0.f, 0.f, 0.f, 0.f};
          sv = MFMA16(af0, b0, sv);
          sv = MFMA16(af1, b1, sv);
          SETPRIO(0);
#pragma unroll
          for (int r = 0; r < 4; r++) sm[r] += fexp2(sv[r]);
        }
      } else {
        const int mg = m0 + wm * 16 + g * 4;   // m for r=0
#pragma unroll
        for (int nf = 0; nf < 4; nf++) {
          const int ni = wn * 4 + nf;
          bf16x8 b0 = frag_ld(qs, ni * 16 + c, 0);
          bf16x8 b1 = frag_ld(qs, ni * 16 + c, 1);
          SETPRIO(1);
          f32x4 sv = {0.f, 0.f, 0.f, 0.f};
          sv = MFMA16(af0, b0, sv);
          sv = MFMA16(af1, b1, sv);
          SETPRIO(0);
          const int ng = nt * 128 + ni * 16 + c;
#pragma unroll
          for (int r = 0; r < 4; r++) {
            float e = fexp2(sv[r]);
            sm[r] += (ng <= mg + r) ? e : 0.f;
          }
        }
      }
    }

#pragma unroll
    for (int r = 0; r < 4; r++) {
      float v = sm[r];
#pragma unroll
      for (int d = 1; d < 16; d <<= 1) v += __shfl_xor(v, d, 64);
      if (c == 0) rbuf[wn][wm * 16 + g * 4 + r] = v;
    }
    WAITCNT("lgkmcnt(0)");
    SBAR();                                    // rbuf visible to all
    {
      const int kd = t >> 3, mc = (t & 7) * 8;
      bf16* p = Vtb + (size_t)kd * N_ + m0 + mc;
      bf16x8 v = *(const bf16x8*)p;
      bf16x8 o;
#pragma unroll
      for (int j = 0; j < 8; j++) {
        const float inv = 1.0f / (rbuf[0][mc + j] + rbuf[1][mc + j]);
        o[j] = bf16bits(bf16f(v[j]) * inv);
      }
      *(bf16x8*)p = o;
    }
  }
}

// ---------------------------------------------------------------------------
// Phase B: out[n][kd] = sum_{m>=n} exp(T[m,n]) * V'[m][kd]  (V pre-divided by
// rowsum, K pre-scaled).  8 waves; QBLK=64, diagonal-paired (qt, 31-qt) ->
// uniform 33 m-tiles.  ONE barrier per tile via PV-lag pipeline:
//   iter mt: lgkm0+SBAR; issue K,V(mt+1); PV(mt-1) [LDS-resident];
//            vmcnt(2) [K,V(mt) landed]; QK(mt) -> P[mt&1].
// K 2-buf, V 3-buf, P 2-buf (56 KB LDS, 2 blocks/CU).  Diagonal peeled.
// QK: wave = (m-frag wm, n-half wn).  PV: wave = (n-frag wm, kd-half wn).
// ---------------------------------------------------------------------------
__global__ __launch_bounds__(512, 4) void phaseB(
    const bf16* __restrict__ Qh, const bf16* __restrict__ Kh,
    const bf16* __restrict__ Vt, bf16* __restrict__ attn) {
  __shared__ char Ksm[2][8192];
  __shared__ char Vsm[3][8192];
  __shared__ char Psm[2][8192];
  const int t = threadIdx.x, lane = t & 63, w = t >> 6;
  const int c = lane & 15, g = lane >> 4;
  const int wm = w & 3, wn = w >> 2;
  const int bid = blockIdx.y * 16 + blockIdx.x;   // 512 blocks
  const int ww = (bid & 7) * 64 + (bid >> 3);     // XCD-contiguous
  const int bx = ww & 15, bh = ww >> 4;
  const int b = bh >> 4, h = bh & 15;
  const int NT = N_ / 64;
  const bf16* Qb = Qh + (size_t)bh * N_ * KD_;
  const bf16* Kb = Kh + (size_t)bh * N_ * KD_;
  const bf16* Vb = Vt + (size_t)bh * KD_ * N_;   // rows kd, stride N_

#pragma unroll 1
  for (int seg = 0; seg < 2; seg++) {
    const int qt = seg ? (31 - bx) : bx;       // 64-row q-tile
    const int n0 = qt * 64, mt0 = qt;

    WAITCNT("lgkmcnt(0)");
    SBAR();                                    // prior-seg LDS reads done
    stageT<64, 512>(Qb + (size_t)n0 * KD_, KD_, Psm[0]);          // 1 load
    stageT<64, 512>(Kb + (size_t)mt0 * 64 * KD_, KD_, Ksm[mt0 & 1]);  // 1
    stageT<64, 512>(Vb + mt0 * 64, N_, Vsm[mt0 % 3]);                 // 1
    WAITCNT("vmcnt(2)");                       // Q landed; K/V in flight
    SBAR();
    bf16x8 qf[2][2];
#pragma unroll
    for (int ni = 0; ni < 2; ni++) {
      qf[ni][0] = frag_ld(Psm[0], wn * 32 + ni * 16 + c, 0);
      qf[ni][1] = frag_ld(Psm[0], wn * 32 + ni * 16 + c, 1);
    }
    WAITCNT("lgkmcnt(0)");
    SBAR();                                    // all waves hold qf; Psm[0] free
    f32x4 out[2] = {};

    // ---- QK for tile mt -> P[mt&1] (mask iff diag) ----
    auto qk_tile = [&](int mt, bool diag) {
      const char* ksm = Ksm[mt & 1];
      bf16x8 kf0 = frag_ld(ksm, wm * 16 + c, 0);
      bf16x8 kf1 = frag_ld(ksm, wm * 16 + c, 1);
      SETPRIO(1);
      f32x4 sv[2];
#pragma unroll
      for (int ni = 0; ni < 2; ni++) {
        f32x4 z = {0.f, 0.f, 0.f, 0.f};
        z = MFMA16(kf0, qf[ni][0], z);
        z = MFMA16(kf1, qf[ni][1], z);
        sv[ni] = z;
      }
      SETPRIO(0);
      const int ml = wm * 16 + g * 4;          // m-local for r=0
      char* ps = Psm[mt & 1];
#pragma unroll
      for (int ni = 0; ni < 2; ni++) {
        const int nl = wn * 32 + ni * 16 + c;  // P^T row (n-local)
        s16x4 p;
#pragma unroll
        for (int r = 0; r < 4; r++) {
          float val = fexp2(sv[ni][r]);
          if (diag && nl > (ml + r)) val = 0.f;
          p[r] = bf16bits(val);
        }
        const int off = nl * 128 + ((wm * 32 + g * 8) ^ ((nl & 7) << 4));
        *(s16x4*)(ps + off) = p;
      }
    };

    // ---- PV for tile mt (reads P[mt&1], V[mt%3]) ----
    auto pv_tile = [&](int mt) {
      const char* ps = Psm[mt & 1];
      const char* vsm = Vsm[mt % 3];
      bf16x8 pa0 = frag_ld(ps, wm * 16 + c, 0);
      bf16x8 pa1 = frag_ld(ps, wm * 16 + c, 1);
      SETPRIO(1);
#pragma unroll
      for (int ni = 0; ni < 2; ni++) {
        const int kdrow = wn * 32 + ni * 16 + c;
        bf16x8 v0 = frag_ld(vsm, kdrow, 0);
        bf16x8 v1 = frag_ld(vsm, kdrow, 1);
        out[ni] = MFMA16(pa0, v0, out[ni]);
        out[ni] = MFMA16(pa1, v1, out[ni]);
      }
      SETPRIO(0);
    };

    // ---- peeled diagonal tile (no PV yet) ----
    if (mt0 + 1 < NT) {
      stageT<64, 512>(Kb + (size_t)(mt0 + 1) * 64 * KD_, KD_, Ksm[(mt0 + 1) & 1]);
      stageT<64, 512>(Vb + (mt0 + 1) * 64, N_, Vsm[(mt0 + 1) % 3]);
      WAITCNT("vmcnt(2)");                     // K,V(mt0) landed
    } else {
      WAITCNT("vmcnt(0)");
    }
    qk_tile(mt0, true);

    // ---- main loop: 1 barrier per tile ----
#pragma unroll 1
    for (int mt = mt0 + 1; mt < NT; mt++) {
      WAITCNT("lgkmcnt(0)");
      SBAR();                                  // P[mt-1] visible; buffers free
      if (mt + 1 < NT) {
        stageT<64, 512>(Kb + (size_t)(mt + 1) * 64 * KD_, KD_, Ksm[(mt + 1) & 1]);
        stageT<64, 512>(Vb + (mt + 1) * 64, N_, Vsm[(mt + 1) % 3]);
      }
      pv_tile(mt - 1);                         // LDS-resident operands
      if (mt + 1 < NT) WAITCNT("vmcnt(2)");    // K,V(mt) landed
      else WAITCNT("vmcnt(0)");
      qk_tile(mt, false);
    }

    WAITCNT("lgkmcnt(0)");
    SBAR();                                    // last P tile visible
    pv_tile(NT - 1);

#pragma unroll
    for (int ni = 0; ni < 2; ni++) {
#pragma unroll
      for (int r = 0; r < 4; r++) {
        const int n = n0 + wm * 16 + g * 4 + r;
        const int kd = wn * 32 + ni * 16 + c;
        attn[((size_t)(b * N_ + n)) * E_ + h * 64 + kd] =
            __float2bfloat16(out[ni][r]);
      }
    }
  }
}

// ---------------------------------------------------------------------------
extern "C" void kernel_launch(void* const* d_in, const int* in_sizes, int n_in,
                              void* d_out, int out_size, void* d_ws, size_t ws_size,
                              hipStream_t stream) {
  (void)in_sizes; (void)n_in; (void)out_size; (void)ws_size;
  const float* x  = (const float*)d_in[0];
  const float* Wq = (const float*)d_in[1];
  const float* bq = (const float*)d_in[2];
  const float* Wk = (const float*)d_in[3];
  const float* bk = (const float*)d_in[4];
  const float* Wv = (const float*)d_in[5];
  const float* bv = (const float*)d_in[6];
  const float* Wp = (const float*)d_in[7];
  const float* bp = (const float*)d_in[8];
  float* out = (float*)d_out;

  const size_t XN = (size_t)M_ * E_;             // 4M elems
  const size_t WN = (size_t)E_ * E_;             // 1M elems
  const size_t HN = (size_t)B_ * H_ * N_ * KD_;  // 4M elems

  bf16* xb   = (bf16*)d_ws;            // reused as attn buffer later
  bf16* wqkv = xb + XN;                // wq|wk|wv contiguous = fused [3E][E]
  bf16* wpb  = wqkv + 3 * WN;
  bf16* Qhd  = wpb + WN;
  bf16* Khd  = Qhd + HN;
  bf16* Vtd  = Khd + HN;
  bf16* attn = xb;                     // xb dead after QKV GEMM

  cvt_all<<<dim3(8192), 256, 0, stream>>>(x, Wq, Wk, Wv, Wp, xb);

  gemm_qkv<<<dim3(24, 32), 256, 0, stream>>>(xb, wqkv, bq, bk, bv,
                                             Qhd, Khd, Vtd);

  phaseA<<<dim3(16, B_ * H_), 512, 0, stream>>>(Khd, Qhd, Vtd);
  phaseB<<<dim3(16, B_ * H_), 512, 0, stream>>>(Qhd, Khd, Vtd, attn);

  gemm_proj<<<dim3(16, 32), 256, 0, stream>>>(attn, wpb, bp, out);
}